// Round 6
// baseline (850.077 us; speedup 1.0000x reference)
//
#include <hip/hip_runtime.h>

// GraphConv: out[t] += input[s] * (esgn*enorm), 3.2M edges, 100K nodes, D=32 fp32.
// Round 6: two-level partition. R5's scatter wrote 198MB (full-line writeback per
// random 8B store). Now: coarse-bucket (512 nodes/bucket) radix partition with
// LDS tile sort -> contiguous run writes; accum fused per bucket with LDS f32
// atomics into a 64KB out-tile; zero global fp32 atomics.

#define NB   256
#define MAXK 256          // max buckets (span 512 -> supports n_nodes <= 131072)
#define SPAN_SHIFT 9      // bucket span = 512 nodes
#define SPAN 512
#define PT   7680         // partition tile edges (30/thread); srec = 60KB LDS

__global__ __launch_bounds__(NB) void hist_kernel(
    const int* __restrict__ tidx, int* __restrict__ bcnt, int n_edges)
{
    __shared__ int lh[MAXK];
    for (int i = threadIdx.x; i < MAXK; i += NB) lh[i] = 0;
    __syncthreads();
    int stride = gridDim.x * NB;
    for (int e = blockIdx.x * NB + threadIdx.x; e < n_edges; e += stride)
        atomicAdd(&lh[tidx[e] >> SPAN_SHIFT], 1);
    __syncthreads();
    for (int i = threadIdx.x; i < MAXK; i += NB)
        if (lh[i]) atomicAdd(&bcnt[i], lh[i]);
}

// Exclusive scan over MAXK bucket counts; writes bbase[0..MAXK] and bcur=bbase.
__global__ __launch_bounds__(MAXK) void scan_kernel(
    const int* __restrict__ bcnt, int* __restrict__ bbase, int* __restrict__ bcur)
{
    __shared__ int part[MAXK];
    int t = threadIdx.x;
    int c = bcnt[t];
    part[t] = c;
    __syncthreads();
    for (int off = 1; off < MAXK; off <<= 1) {
        int v = (t >= off) ? part[t - off] : 0;
        __syncthreads();
        part[t] += v;
        __syncthreads();
    }
    int excl = part[t] - c;
    bbase[t] = excl;
    bcur[t] = excl;
    if (t == MAXK - 1) bbase[MAXK] = part[MAXK - 1];
}

// Tile-local sort into buckets, then contiguous run writes to global.
__global__ __launch_bounds__(NB) void partition_kernel(
    const int* __restrict__ sidx, const int* __restrict__ tidx,
    const float* __restrict__ enorm, const float* __restrict__ esgn,
    int* __restrict__ bcur, int2* __restrict__ recs, int n_edges)
{
    __shared__ int2 srec[PT];              // 60 KB
    __shared__ int lh[MAXK];               // tile counts
    __shared__ int lbase[MAXK];            // tile-local exclusive base (scan buf)
    __shared__ int lcur[MAXK];             // tile-local cursors
    __shared__ int gb[MAXK];               // global run base for this tile
    int t = threadIdx.x;
    lh[t] = 0;
    __syncthreads();

    size_t tb = (size_t)blockIdx.x * PT;
    // pass 1: tile histogram
    for (int j = 0; j < PT / NB; ++j) {
        int e = (int)tb + j * NB + t;
        if (e < n_edges) atomicAdd(&lh[tidx[e] >> SPAN_SHIFT], 1);
    }
    __syncthreads();
    // tile scan (Hillis-Steele over MAXK == NB)
    int c = lh[t];
    lbase[t] = c;
    __syncthreads();
    for (int off = 1; off < MAXK; off <<= 1) {
        int v = (t >= off) ? lbase[t - off] : 0;
        __syncthreads();
        lbase[t] += v;
        __syncthreads();
    }
    int excl = lbase[t] - c;
    __syncthreads();
    lbase[t] = excl;
    lcur[t] = excl;
    if (c > 0) gb[t] = atomicAdd(&bcur[t], c);   // reserve global run
    __syncthreads();
    // pass 2: scatter tile records into LDS in bucket order
    for (int j = 0; j < PT / NB; ++j) {
        int e = (int)tb + j * NB + t;
        if (e < n_edges) {
            int tn = tidx[e];
            int b = tn >> SPAN_SHIFT;
            unsigned rec = ((unsigned)sidx[e] << SPAN_SHIFT) | (unsigned)(tn & (SPAN - 1));
            float w = enorm[e] * esgn[e];
            int p = atomicAdd(&lcur[b], 1);
            srec[p] = make_int2((int)rec, __float_as_int(w));
        }
    }
    __syncthreads();
    // write out: thread t streams bucket t's run contiguously
    int cnt = lh[t];
    if (cnt > 0) {
        int lb = lbase[t];
        int g = gb[t];
        for (int i = 0; i < cnt; ++i) recs[g + i] = srec[lb + i];
    }
}

// One block per bucket: LDS out-tile (512 nodes x 32 feats), LDS f32 atomics.
__global__ __launch_bounds__(1024) void accum_kernel(
    const float* __restrict__ input, const int2* __restrict__ recs,
    const int* __restrict__ bbase, float* __restrict__ out, int n_nodes)
{
    __shared__ float acc[SPAN * 32];       // 64 KB
    int b = blockIdx.x;
    for (int i = threadIdx.x; i < SPAN * 32; i += 1024) acc[i] = 0.f;
    __syncthreads();
    int beg = bbase[b], end = bbase[b + 1];
    int g = threadIdx.x >> 5;              // 32 groups of 32 lanes
    int f = threadIdx.x & 31;
    for (int i = beg + g; i < end; i += 32) {
        int2 r = recs[i];                  // broadcast within group
        float w = __int_as_float(r.y);
        unsigned u = (unsigned)r.x;
        int s = (int)(u >> SPAN_SHIFT);
        int ln = (int)(u & (SPAN - 1));
        atomicAdd(&acc[ln * 32 + f], w * input[(size_t)s * 32 + f]);
    }
    __syncthreads();
    size_t obase = (size_t)b * SPAN * 32;
    int lim = n_nodes * 32 - (int)obase;   // partial last bucket
    for (int i = threadIdx.x; i < SPAN * 32; i += 1024)
        if (i < lim) out[obase + i] = acc[i];
}

// Fallback (R3): direct atomic scatter, used only if ws/shape checks fail.
__global__ __launch_bounds__(NB) void graphconv_scatter(
    const float* __restrict__ input, const int* __restrict__ sidx,
    const int* __restrict__ tidx, const float* __restrict__ enorm,
    const float* __restrict__ esgn, float* __restrict__ out, int n_edges)
{
    int t = blockIdx.x * NB + threadIdx.x;
    int e = t >> 3;
    int sub = t & 7;
    if (e >= n_edges) return;
    int s = sidx[e];
    int d = tidx[e];
    float w = enorm[e] * esgn[e];
    const float4* src = (const float4*)(input + (size_t)s * 32);
    float4 v = src[sub];
    float* op = out + (size_t)d * 32 + sub * 4;
    atomicAdd(op + 0, v.x * w);
    atomicAdd(op + 1, v.y * w);
    atomicAdd(op + 2, v.z * w);
    atomicAdd(op + 3, v.w * w);
}

extern "C" void kernel_launch(void* const* d_in, const int* in_sizes, int n_in,
                              void* d_out, int out_size, void* d_ws, size_t ws_size,
                              hipStream_t stream) {
    const float* input = (const float*)d_in[0];
    const int*   eidx  = (const int*)d_in[1];   // int64 in reference -> int32 here
    const float* enorm = (const float*)d_in[2];
    const float* esgn  = (const float*)d_in[3];
    float*       out   = (float*)d_out;

    int n_edges = in_sizes[1] / 2;             // eidx is (2, n_edges)
    int n_nodes = in_sizes[0] / 32;            // input is (n_nodes, 32)
    const int* sidx = eidx;
    const int* tidx = eidx + n_edges;

    int K = (n_nodes + SPAN - 1) >> SPAN_SHIFT;

    // Workspace: recs[int2 x n_edges] | bcnt[MAXK] | bcur[MAXK] | bbase[MAXK+1]
    size_t need = (size_t)n_edges * 8 + ((size_t)3 * MAXK + 1) * 4;

    if (ws_size >= need && K <= MAXK && n_nodes <= (MAXK << SPAN_SHIFT)) {
        int2* recs  = (int2*)d_ws;
        int*  bcnt  = (int*)(recs + n_edges);
        int*  bcur  = bcnt + MAXK;
        int*  bbase = bcur + MAXK;

        hipMemsetAsync(bcnt, 0, MAXK * sizeof(int), stream);

        hist_kernel     <<<1024, NB,   0, stream>>>(tidx, bcnt, n_edges);
        scan_kernel     <<<1,    MAXK, 0, stream>>>(bcnt, bbase, bcur);
        int pg = (n_edges + PT - 1) / PT;
        partition_kernel<<<pg,   NB,   0, stream>>>(sidx, tidx, enorm, esgn,
                                                    bcur, recs, n_edges);
        accum_kernel    <<<K,    1024, 0, stream>>>(input, recs, bbase, out,
                                                    n_nodes);
    } else {
        hipMemsetAsync(d_out, 0, (size_t)out_size * sizeof(float), stream);
        size_t threads_total = (size_t)n_edges * 8;
        int grid = (int)((threads_total + NB - 1) / NB);
        graphconv_scatter<<<grid, NB, 0, stream>>>(input, sidx, tidx, enorm, esgn,
                                                   out, n_edges);
    }
}

// Round 7
// 840.396 us; speedup vs baseline: 1.0115x; 1.0115x over previous
//
#include <hip/hip_runtime.h>

// GraphConv: out[t] += input[s] * (esgn*enorm), 3.2M edges, 100K nodes, D=32 fp32.
// Round 7: R6 structure, but accum inner loop gets explicit 8x batch unroll.
// R6 post-mortem: accum was pure dependent-load latency (6272 chains x 2600
// edges x ~650cyc = 702us, matched measurement). Batched independent loads
// give ~8x memory-level parallelism per chain.

#define NB   256
#define MAXK 256          // max buckets (span 512 -> supports n_nodes <= 131072)
#define SPAN_SHIFT 9      // bucket span = 512 nodes
#define SPAN 512
#define PT   7680         // partition tile edges (30/thread); srec = 60KB LDS
#define UNROLL 8

__global__ __launch_bounds__(NB) void hist_kernel(
    const int* __restrict__ tidx, int* __restrict__ bcnt, int n_edges)
{
    __shared__ int lh[MAXK];
    for (int i = threadIdx.x; i < MAXK; i += NB) lh[i] = 0;
    __syncthreads();
    int stride = gridDim.x * NB;
    for (int e = blockIdx.x * NB + threadIdx.x; e < n_edges; e += stride)
        atomicAdd(&lh[tidx[e] >> SPAN_SHIFT], 1);
    __syncthreads();
    for (int i = threadIdx.x; i < MAXK; i += NB)
        if (lh[i]) atomicAdd(&bcnt[i], lh[i]);
}

// Exclusive scan over MAXK bucket counts; writes bbase[0..MAXK] and bcur=bbase.
__global__ __launch_bounds__(MAXK) void scan_kernel(
    const int* __restrict__ bcnt, int* __restrict__ bbase, int* __restrict__ bcur)
{
    __shared__ int part[MAXK];
    int t = threadIdx.x;
    int c = bcnt[t];
    part[t] = c;
    __syncthreads();
    for (int off = 1; off < MAXK; off <<= 1) {
        int v = (t >= off) ? part[t - off] : 0;
        __syncthreads();
        part[t] += v;
        __syncthreads();
    }
    int excl = part[t] - c;
    bbase[t] = excl;
    bcur[t] = excl;
    if (t == MAXK - 1) bbase[MAXK] = part[MAXK - 1];
}

// Tile-local sort into buckets, then contiguous run writes to global.
__global__ __launch_bounds__(NB) void partition_kernel(
    const int* __restrict__ sidx, const int* __restrict__ tidx,
    const float* __restrict__ enorm, const float* __restrict__ esgn,
    int* __restrict__ bcur, int2* __restrict__ recs, int n_edges)
{
    __shared__ int2 srec[PT];              // 60 KB
    __shared__ int lh[MAXK];
    __shared__ int lbase[MAXK];
    __shared__ int lcur[MAXK];
    __shared__ int gb[MAXK];
    int t = threadIdx.x;
    lh[t] = 0;
    __syncthreads();

    size_t tb = (size_t)blockIdx.x * PT;
    for (int j = 0; j < PT / NB; ++j) {
        int e = (int)tb + j * NB + t;
        if (e < n_edges) atomicAdd(&lh[tidx[e] >> SPAN_SHIFT], 1);
    }
    __syncthreads();
    int c = lh[t];
    lbase[t] = c;
    __syncthreads();
    for (int off = 1; off < MAXK; off <<= 1) {
        int v = (t >= off) ? lbase[t - off] : 0;
        __syncthreads();
        lbase[t] += v;
        __syncthreads();
    }
    int excl = lbase[t] - c;
    __syncthreads();
    lbase[t] = excl;
    lcur[t] = excl;
    if (c > 0) gb[t] = atomicAdd(&bcur[t], c);
    __syncthreads();
    for (int j = 0; j < PT / NB; ++j) {
        int e = (int)tb + j * NB + t;
        if (e < n_edges) {
            int tn = tidx[e];
            int b = tn >> SPAN_SHIFT;
            unsigned rec = ((unsigned)sidx[e] << SPAN_SHIFT) | (unsigned)(tn & (SPAN - 1));
            float w = enorm[e] * esgn[e];
            int p = atomicAdd(&lcur[b], 1);
            srec[p] = make_int2((int)rec, __float_as_int(w));
        }
    }
    __syncthreads();
    int cnt = lh[t];
    if (cnt > 0) {
        int lb = lbase[t];
        int g = gb[t];
        for (int i = 0; i < cnt; ++i) recs[g + i] = srec[lb + i];
    }
}

// One block per bucket: LDS out-tile (512 x 32 fp32), LDS f32 atomics.
// 8x batched loads for memory-level parallelism.
__global__ __launch_bounds__(1024) void accum_kernel(
    const float* __restrict__ input, const int2* __restrict__ recs,
    const int* __restrict__ bbase, float* __restrict__ out, int n_nodes)
{
    __shared__ float acc[SPAN * 32];       // 64 KB
    int b = blockIdx.x;
    for (int i = threadIdx.x; i < SPAN * 32; i += 1024) acc[i] = 0.f;
    __syncthreads();
    int beg = bbase[b], end = bbase[b + 1];
    int g = threadIdx.x >> 5;              // 32 groups of 32 lanes
    int f = threadIdx.x & 31;

    int B = beg;
    for (; B + 32 * UNROLL <= end; B += 32 * UNROLL) {
        int2 r[UNROLL];
#pragma unroll
        for (int u = 0; u < UNROLL; ++u)
            r[u] = recs[B + g + 32 * u];           // 8 independent loads
        float v[UNROLL];
#pragma unroll
        for (int u = 0; u < UNROLL; ++u) {
            int s = (int)(((unsigned)r[u].x) >> SPAN_SHIFT);
            v[u] = input[(size_t)s * 32 + f];      // 8 independent gathers
        }
#pragma unroll
        for (int u = 0; u < UNROLL; ++u) {
            int ln = r[u].x & (SPAN - 1);
            atomicAdd(&acc[ln * 32 + f], __int_as_float(r[u].y) * v[u]);
        }
    }
    for (int i = B + g; i < end; i += 32) {        // tail
        int2 r = recs[i];
        int s = (int)(((unsigned)r.x) >> SPAN_SHIFT);
        int ln = r.x & (SPAN - 1);
        atomicAdd(&acc[ln * 32 + f], __int_as_float(r.y) * input[(size_t)s * 32 + f]);
    }
    __syncthreads();
    size_t obase = (size_t)b * SPAN * 32;
    int lim = n_nodes * 32 - (int)obase;
    for (int i = threadIdx.x; i < SPAN * 32; i += 1024)
        if (i < lim) out[obase + i] = acc[i];
}

// Fallback (R3): direct atomic scatter, used only if ws/shape checks fail.
__global__ __launch_bounds__(NB) void graphconv_scatter(
    const float* __restrict__ input, const int* __restrict__ sidx,
    const int* __restrict__ tidx, const float* __restrict__ enorm,
    const float* __restrict__ esgn, float* __restrict__ out, int n_edges)
{
    int t = blockIdx.x * NB + threadIdx.x;
    int e = t >> 3;
    int sub = t & 7;
    if (e >= n_edges) return;
    int s = sidx[e];
    int d = tidx[e];
    float w = enorm[e] * esgn[e];
    const float4* src = (const float4*)(input + (size_t)s * 32);
    float4 v = src[sub];
    float* op = out + (size_t)d * 32 + sub * 4;
    atomicAdd(op + 0, v.x * w);
    atomicAdd(op + 1, v.y * w);
    atomicAdd(op + 2, v.z * w);
    atomicAdd(op + 3, v.w * w);
}

extern "C" void kernel_launch(void* const* d_in, const int* in_sizes, int n_in,
                              void* d_out, int out_size, void* d_ws, size_t ws_size,
                              hipStream_t stream) {
    const float* input = (const float*)d_in[0];
    const int*   eidx  = (const int*)d_in[1];   // int64 in reference -> int32 here
    const float* enorm = (const float*)d_in[2];
    const float* esgn  = (const float*)d_in[3];
    float*       out   = (float*)d_out;

    int n_edges = in_sizes[1] / 2;             // eidx is (2, n_edges)
    int n_nodes = in_sizes[0] / 32;            // input is (n_nodes, 32)
    const int* sidx = eidx;
    const int* tidx = eidx + n_edges;

    int K = (n_nodes + SPAN - 1) >> SPAN_SHIFT;

    // Workspace: recs[int2 x n_edges] | bcnt[MAXK] | bcur[MAXK] | bbase[MAXK+1]
    size_t need = (size_t)n_edges * 8 + ((size_t)3 * MAXK + 1) * 4;

    if (ws_size >= need && K <= MAXK && n_nodes <= (MAXK << SPAN_SHIFT)) {
        int2* recs  = (int2*)d_ws;
        int*  bcnt  = (int*)(recs + n_edges);
        int*  bcur  = bcnt + MAXK;
        int*  bbase = bcur + MAXK;

        hipMemsetAsync(bcnt, 0, MAXK * sizeof(int), stream);

        hist_kernel     <<<1024, NB,   0, stream>>>(tidx, bcnt, n_edges);
        scan_kernel     <<<1,    MAXK, 0, stream>>>(bcnt, bbase, bcur);
        int pg = (n_edges + PT - 1) / PT;
        partition_kernel<<<pg,   NB,   0, stream>>>(sidx, tidx, enorm, esgn,
                                                    bcur, recs, n_edges);
        accum_kernel    <<<K,    1024, 0, stream>>>(input, recs, bbase, out,
                                                    n_nodes);
    } else {
        hipMemsetAsync(d_out, 0, (size_t)out_size * sizeof(float), stream);
        size_t threads_total = (size_t)n_edges * 8;
        int grid = (int)((threads_total + NB - 1) / NB);
        graphconv_scatter<<<grid, NB, 0, stream>>>(input, sidx, tidx, enorm, esgn,
                                                   out, n_edges);
    }
}